// Round 9
// baseline (251.134 us; speedup 1.0000x reference)
//
#include <hip/hip_runtime.h>

#define NN 20000
#define NE 640000
#define NET (NE + NN)   // 660000 edges incl. self-loops
#define NB 128          // dst buckets
#define RR 157          // nodes per bucket (ceil 20000/128)
#define NSL 256         // edge slices
#define ESL4 625        // int4 per slice (2500 edges)

typedef __attribute__((ext_vector_type(8))) short bf16x8;
typedef __attribute__((ext_vector_type(4))) float f32x4;

__device__ inline ushort f2bf_rne(float x) {
    unsigned u = __float_as_uint(x);
    return (ushort)((u + 0x7FFFu + ((u >> 16) & 1u)) >> 16);
}
__device__ inline void split2(float x, ushort& hi, ushort& lo) {
    unsigned u = __float_as_uint(x);
    unsigned r = (u + 0x7FFFu + ((u >> 16) & 1u)) & 0xFFFF0000u;  // RNE to bf16
    hi = (ushort)(r >> 16);
    lo = f2bf_rne(x - __uint_as_float(r));   // x - hi is exact
}
__device__ inline float rlane(float x, int k) {
    return __int_as_float(__builtin_amdgcn_readlane(__float_as_int(x), k));
}

// ---- csrA: per-slice bucket histogram + fold_w1 + weight pre-splits ----
__global__ void csrA_kernel(const int* __restrict__ ei, int* __restrict__ cnt,
                            const float* __restrict__ W1, const float* __restrict__ as1,
                            const float* __restrict__ ad1, float* __restrict__ w1f,
                            const float* __restrict__ W2, const float* __restrict__ W_ih,
                            const float* __restrict__ W_I, const float* __restrict__ b_I,
                            const float* __restrict__ W_R, const float* __restrict__ b_R,
                            const float* __restrict__ W_sir, const float* __restrict__ b_sir,
                            ushort* __restrict__ w1bh, ushort* __restrict__ w1bl,
                            ushort* __restrict__ w2bh, ushort* __restrict__ w2bl,
                            ushort* __restrict__ w3bh, ushort* __restrict__ w3bl,
                            ushort* __restrict__ wthb, ushort* __restrict__ wtlb,
                            float* __restrict__ wc, float* __restrict__ wb) {
    int b = blockIdx.x, t = threadIdx.x;
    if (b < NSL) {
        __shared__ int h[NB];
        if (t < NB) h[t] = 0;
        __syncthreads();
        const int4* d4 = (const int4*)(ei + NE);
        for (int i = t; i < ESL4; i += 256) {
            int4 d = d4[b * ESL4 + i];
            atomicAdd(&h[(unsigned)d.x / RR], 1);
            atomicAdd(&h[(unsigned)d.y / RR], 1);
            atomicAdd(&h[(unsigned)d.z / RR], 1);
            atomicAdd(&h[(unsigned)d.w / RR], 1);
        }
        __syncthreads();
        if (t < NB) cnt[t * NSL + b] = h[t];   // bucket-major
    } else if (b == NSL) {
        if (t < 128) {
            int k = t;
#pragma unroll
            for (int hh = 0; hh < 4; hh++) {
                float s1 = 0.f, s2 = 0.f;
                for (int c = 0; c < 64; c++) {
                    float w = W1[k * 256 + hh * 64 + c];
                    s1 += w * as1[hh * 64 + c];
                    s2 += w * ad1[hh * 64 + c];
                }
                w1f[k * 8 + hh] = s1;
                w1f[k * 8 + 4 + hh] = s2;
            }
        }
    } else if (b == NSL + 1) {
        // heads: Wt[128][32] bf16 split + wc (cols 128/129) + wb
        if (t < 128) {
            for (int p = 0; p < 32; p++) {
                const float* Wr = (p < 15) ? W_I + p * 130
                                : (p < 30) ? W_R + (p - 15) * 130
                                           : W_sir + (p - 30) * 130;
                ushort h, l;
                split2(Wr[t], h, l);
                wthb[t * 32 + p] = h;
                wtlb[t * 32 + p] = l;
            }
        } else if (t < 160) {
            int p = t - 128;
            const float* Wr = (p < 15) ? W_I + p * 130
                            : (p < 30) ? W_R + (p - 15) * 130
                                       : W_sir + (p - 30) * 130;
            wc[p * 2] = Wr[128];
            wc[p * 2 + 1] = Wr[129];
            wb[p] = (p < 15) ? b_I[p] : (p < 30) ? b_R[p - 15] : b_sir[p - 30];
        }
    } else if (b == NSL + 2) {
        for (int i = t; i < 128 * 256; i += 256) {
            ushort h, l; split2(W1[i], h, l);
            w1bh[i] = h; w1bl[i] = l;
        }
    } else if (b == NSL + 3) {
        for (int i = t; i < 256 * 128; i += 256) {
            ushort h, l; split2(W2[i], h, l);
            w2bh[i] = h; w2bl[i] = l;
        }
    } else {
        // W_ih^T: out[c][r] (c<128, r<384) = W_ih[r][c]
        for (int i = t; i < 128 * 384; i += 256) {
            int c = i / 384, r = i % 384;
            ushort h, l; split2(W_ih[r * 128 + c], h, l);
            w3bh[i] = h; w3bl[i] = l;
        }
    }
}

// ---- csrB: exclusive scan of 32768 counts (bucket-major) ----
__global__ void csrB_kernel(const int* __restrict__ cnt, int* __restrict__ sbase) {
    __shared__ int swsum[16], swsum2[16];
    __shared__ int s_carry;
    int t = threadIdx.x, wv = t >> 6, ln = t & 63;
    if (t == 0) s_carry = 0;
    __syncthreads();
    for (int base = 0; base < NB * NSL; base += 1024) {
        int v = cnt[base + t];
        int s = v;
#pragma unroll
        for (int o = 1; o < 64; o <<= 1) { int u = __shfl_up(s, o, 64); if (ln >= o) s += u; }
        if (ln == 63) swsum[wv] = s;
        __syncthreads();
        if (t < 16) {
            int sv = swsum[t];
#pragma unroll
            for (int o = 1; o < 16; o <<= 1) { int u = __shfl_up(sv, o, 16); if (t >= o) sv += u; }
            swsum2[t] = sv;
        }
        __syncthreads();
        sbase[base + t] = s_carry + (wv ? swsum2[wv - 1] : 0) + s - v;
        __syncthreads();
        if (t == 0) s_carry += swsum2[15];
        __syncthreads();
    }
}

// ---- csrC: slice scatter into ebuf + alar_cast ----
__global__ void csrC_kernel(const int* __restrict__ ei, const int* __restrict__ sbase,
                            int2* __restrict__ ebuf, const float* __restrict__ X,
                            const float* __restrict__ wf, ushort* __restrict__ Xbf,
                            float* __restrict__ al, float* __restrict__ ar) {
    int b = blockIdx.x, t = threadIdx.x;
    if (b < NSL) {
        __shared__ int cur[NB];
        if (t < NB) cur[t] = sbase[t * NSL + b];
        __syncthreads();
        const int4* s4 = (const int4*)ei;
        const int4* d4 = (const int4*)(ei + NE);
        for (int i = t; i < ESL4; i += 256) {
            int4 sv = s4[b * ESL4 + i];
            int4 dv = d4[b * ESL4 + i];
            int p;
            p = atomicAdd(&cur[(unsigned)dv.x / RR], 1); ebuf[p] = make_int2(sv.x, dv.x);
            p = atomicAdd(&cur[(unsigned)dv.y / RR], 1); ebuf[p] = make_int2(sv.y, dv.y);
            p = atomicAdd(&cur[(unsigned)dv.z / RR], 1); ebuf[p] = make_int2(sv.z, dv.z);
            p = atomicAdd(&cur[(unsigned)dv.w / RR], 1); ebuf[p] = make_int2(sv.w, dv.w);
        }
    } else {
        __shared__ float ws[8][128];
        for (int i = t; i < 1024; i += 256) ws[i & 7][i >> 3] = wf[i];
        __syncthreads();
        int wv = t >> 6, ln = t & 63;
        int n = (b - NSL) * 4 + wv;
        float2 xv = *(const float2*)(X + (size_t)n * 128 + ln * 2);
        ushort2 ub;
        ub.x = f2bf_rne(xv.x);
        ub.y = f2bf_rne(xv.y);
        *(ushort2*)(Xbf + (size_t)n * 128 + ln * 2) = ub;
        float p[8];
#pragma unroll
        for (int o = 0; o < 8; o++) p[o] = xv.x * ws[o][ln * 2] + xv.y * ws[o][ln * 2 + 1];
#pragma unroll
        for (int off = 32; off > 0; off >>= 1)
#pragma unroll
            for (int o = 0; o < 8; o++) p[o] += __shfl_xor(p[o], off, 64);
        if (ln == 0) {
#pragma unroll
            for (int h = 0; h < 4; h++) {
                al[n * 4 + h] = p[h];
                ar[n * 4 + h] = p[4 + h];
            }
        }
    }
}

// ---- csrD: per-bucket local CSR build ----
__global__ void csrD_kernel(const int2* __restrict__ ebuf, const int* __restrict__ sbase,
                            int* __restrict__ offs, int* __restrict__ csr_src) {
    __shared__ int hist[RR], lcur[RR];
    int b = blockIdx.x, t = threadIdx.x;
    int lo = b * RR;
    int Ra = min(RR, NN - lo);
    int e0 = sbase[b * NSL];
    int e1 = (b < NB - 1) ? sbase[(b + 1) * NSL] : NE;
    int m = e1 - e0;
    for (int i = t; i < Ra; i += 256) hist[i] = 0;
    __syncthreads();
    for (int j = t; j < m; j += 256) atomicAdd(&hist[ebuf[e0 + j].y - lo], 1);
    __syncthreads();
    if (t < 64) {
        int cbase = e0 + lo;
        int carry = 0;
#pragma unroll
        for (int c = 0; c < 3; c++) {
            int i = c * 64 + t;
            int v = (i < Ra) ? hist[i] + 1 : 0;   // +1 self-loop
            int s = v;
#pragma unroll
            for (int o = 1; o < 64; o <<= 1) { int u = __shfl_up(s, o, 64); if (t >= o) s += u; }
            if (i < Ra) {
                int off = cbase + carry + s - v;
                offs[lo + i] = off;
                lcur[i] = off;
            }
            carry += __shfl(s, 63, 64);
        }
    }
    if (b == 0 && t == 255) offs[NN] = NET;
    __syncthreads();
    for (int i = t; i < Ra; i += 256) csr_src[lcur[i] + hist[i]] = lo + i;  // self-loop last
    __syncthreads();
    for (int j = t; j < m; j += 256) {
        int2 p = ebuf[e0 + j];
        int pos = atomicAdd(&lcur[p.y - lo], 1);
        csr_src[pos] = p.x;
    }
}

// ---- layer-2 al/ar from xl2_bf ----
__launch_bounds__(256)
__global__ void alar_apply2(const ushort* __restrict__ Xbf, const float* __restrict__ a_src,
                            const float* __restrict__ a_dst, float* __restrict__ al,
                            float* __restrict__ ar) {
    __shared__ float wsa[128], wsd[128];
    int t = threadIdx.x;
    if (t < 128) { wsa[t] = a_src[t]; wsd[t] = a_dst[t]; }
    __syncthreads();
    int wv = t >> 6, ln = t & 63;
    int n = blockIdx.x * 4 + wv;
    ushort2 u = *(const ushort2*)(Xbf + (size_t)n * 128 + ln * 2);
    float x0 = __uint_as_float(((unsigned)u.x) << 16);
    float x1 = __uint_as_float(((unsigned)u.y) << 16);
    float p0 = x0 * wsa[ln * 2] + x1 * wsa[ln * 2 + 1];
    float p1 = x0 * wsd[ln * 2] + x1 * wsd[ln * 2 + 1];
#pragma unroll
    for (int off = 32; off > 0; off >>= 1) {
        p0 += __shfl_xor(p0, off, 64);
        p1 += __shfl_xor(p1, off, 64);
    }
    if (ln == 0) { al[n] = p0; ar[n] = p1; }
}

// ---- GAT gather: wave/node, NO max-pass softmax (shift-invariant, logits tiny) ----
template <int H, bool FUSE>
__launch_bounds__(256)
__global__ void gat_gather_w(const ushort* __restrict__ X, const float* __restrict__ al,
                             const float* __restrict__ ar, const int* __restrict__ offs,
                             const int* __restrict__ csr, const float* __restrict__ bias,
                             void* __restrict__ outp) {
    int t = threadIdx.x;
    int wv = t >> 6, ln = t & 63;
    int n = blockIdx.x * 4 + wv;
    int e0 = offs[n], e1 = offs[n + 1];

    float arv[H], srun[H], acc0[H], acc1[H];
#pragma unroll
    for (int h = 0; h < H; h++) {
        arv[h] = ar[n * H + h];
        srun[h] = 0.f; acc0[h] = 0.f; acc1[h] = 0.f;
    }
    const ushort* Xc = X + ln * 2;

    for (int base = e0; base < e1; base += 64) {
        int cnt = e1 - base; if (cnt > 64) cnt = 64;
        bool vld = ln < cnt;
        int src = vld ? csr[base + ln] : 0;
        float wgt[H];
        {
            float av[H];
            if (H == 4) {
                float4 a4 = *(const float4*)(al + (size_t)src * 4);
                av[0] = a4.x; av[H > 1 ? 1 : 0] = a4.y;
                av[H > 2 ? 2 : 0] = a4.z; av[H > 3 ? 3 : 0] = a4.w;
            } else {
                av[0] = al[src];
            }
#pragma unroll
            for (int h = 0; h < H; h++) {
                float lg = av[h] + arv[h];
                lg = lg > 0.f ? lg : 0.2f * lg;
                wgt[h] = vld ? __expf(lg) : 0.f;
            }
        }
        float ls[H];
#pragma unroll
        for (int h = 0; h < H; h++) ls[h] = wgt[h];
#pragma unroll
        for (int off = 32; off > 0; off >>= 1)
#pragma unroll
            for (int h = 0; h < H; h++) ls[h] += __shfl_xor(ls[h], off, 64);
#pragma unroll
        for (int h = 0; h < H; h++) srun[h] += ls[h];

        int k = 0;
        for (; k + 8 <= cnt; k += 8) {
            int s[8];
            unsigned u[8];
#pragma unroll
            for (int q = 0; q < 8; q++) s[q] = __builtin_amdgcn_readlane(src, k + q);
#pragma unroll
            for (int q = 0; q < 8; q++) u[q] = *(const unsigned*)(Xc + (size_t)s[q] * 128);
#pragma unroll
            for (int h = 0; h < H; h++) {
#pragma unroll
                for (int q = 0; q < 8; q++) {
                    float w = rlane(wgt[h], k + q);
                    acc0[h] = fmaf(w, __uint_as_float(u[q] << 16), acc0[h]);
                    acc1[h] = fmaf(w, __uint_as_float(u[q] & 0xffff0000u), acc1[h]);
                }
            }
        }
        for (; k < cnt; k++) {
            int s0 = __builtin_amdgcn_readlane(src, k);
            unsigned u0 = *(const unsigned*)(Xc + (size_t)s0 * 128);
            float x00 = __uint_as_float(u0 << 16), x01 = __uint_as_float(u0 & 0xffff0000u);
#pragma unroll
            for (int h = 0; h < H; h++) {
                float w0 = rlane(wgt[h], k);
                acc0[h] = fmaf(w0, x00, acc0[h]); acc1[h] = fmaf(w0, x01, acc1[h]);
            }
        }
    }
    if (FUSE) {
        ushort* out = (ushort*)outp;
        float inv = 1.f / srun[0];
        float v0 = acc0[0] * inv + bias[ln * 2];
        float v1 = acc1[0] * inv + bias[ln * 2 + 1];
        v0 = v0 > 0.f ? v0 : __expf(v0) - 1.f;
        v1 = v1 > 0.f ? v1 : __expf(v1) - 1.f;
        ushort2 o;
        o.x = f2bf_rne(v0);
        o.y = f2bf_rne(v1);
        *(ushort2*)(out + (size_t)n * 128 + ln * 2) = o;
    } else {
        ushort* out = (ushort*)outp;
#pragma unroll
        for (int h = 0; h < H; h++) {
            float inv = 1.f / srun[h];
            ushort2 o;
            o.x = f2bf_rne(acc0[h] * inv);
            o.y = f2bf_rne(acc1[h] * inv);
            *(ushort2*)(out + (size_t)n * (H * 128) + h * 128 + ln * 2) = o;
        }
    }
}

// ---- MFMA bf16 GEMM: A bf16, B pre-split hi/lo bf16 (2-term, near-f32 B) ----
template <int ACT, bool OUTBF, int BN>
__launch_bounds__(256)
__global__ void gemm_bf(const ushort* __restrict__ A, const ushort* __restrict__ Bh_pre,
                        const ushort* __restrict__ Bl_pre, const float* __restrict__ bias,
                        void* __restrict__ Cptr, int M, int K, int lda, int ldb, int ldc,
                        int zA, int zB, int zC) {
    constexpr int NF = BN / 32;
    __shared__ ushort Ah[128 * 64];
    __shared__ ushort Bh[64 * BN];
    __shared__ ushort Bl[64 * BN];
    int tid = threadIdx.x;
    int z = blockIdx.z;
    int bm = blockIdx.x * 128;
    int ny = blockIdx.y * BN;
    int wid = tid >> 6, ln = tid & 63;
    int wm = wid >> 1, wn = wid & 1;
    f32x4 acc[4][NF];
#pragma unroll
    for (int a = 0; a < 4; a++)
#pragma unroll
        for (int b = 0; b < NF; b++)
#pragma unroll
            for (int j = 0; j < 4; j++) acc[a][b][j] = 0.f;
    size_t abase = (size_t)z * zA;
    int bcb = z * zB + ny;

    for (int k0 = 0; k0 < K; k0 += 64) {
#pragma unroll
        for (int i = 0; i < 8; i++) {
            int idx = tid + i * 256;
            int r = idx >> 4, c4 = (idx & 15) * 4;
            int gr = bm + r;
            ushort4 v = make_ushort4(0, 0, 0, 0);
            if (gr < M) v = *(const ushort4*)(A + abase + (size_t)gr * lda + k0 + c4);
            int ab = (r * 128 + c4 * 2) ^ ((r & 7) << 4);
            *(ushort4*)((char*)Ah + ab) = v;
        }
#pragma unroll
        for (int i = 0; i < BN / 16; i++) {
            int idx = tid + i * 256;
            int kk = idx / (BN / 4);
            int c4 = (idx % (BN / 4)) * 4;
            size_t gb = (size_t)(k0 + kk) * ldb + bcb + c4;
            ushort4 vh = *(const ushort4*)(Bh_pre + gb);
            ushort4 vl = *(const ushort4*)(Bl_pre + gb);
            ushort hh[4] = {vh.x, vh.y, vh.z, vh.w};
            ushort ll[4] = {vl.x, vl.y, vl.z, vl.w};
#pragma unroll
            for (int q = 0; q < 4; q++) {
                int nl = c4 + q;
                int bb = (nl * 128 + kk * 2) ^ ((nl & 7) << 4);
                *(ushort*)((char*)Bh + bb) = hh[q];
                *(ushort*)((char*)Bl + bb) = ll[q];
            }
        }
        __syncthreads();
#pragma unroll
        for (int ks = 0; ks < 2; ks++) {
            int kb = ks * 64 + (ln >> 4) * 16;
            bf16x8 ah[4], bh[NF], bl[NF];
#pragma unroll
            for (int mf = 0; mf < 4; mf++) {
                int r = wm * 64 + mf * 16 + (ln & 15);
                int ab = (r * 128 + kb) ^ ((r & 7) << 4);
                ah[mf] = *(bf16x8*)((char*)Ah + ab);
            }
#pragma unroll
            for (int nf = 0; nf < NF; nf++) {
                int nl = wn * (BN / 2) + nf * 16 + (ln & 15);
                int bb = (nl * 128 + kb) ^ ((nl & 7) << 4);
                bh[nf] = *(bf16x8*)((char*)Bh + bb);
                bl[nf] = *(bf16x8*)((char*)Bl + bb);
            }
#pragma unroll
            for (int mf = 0; mf < 4; mf++)
#pragma unroll
                for (int nf = 0; nf < NF; nf++) {
                    acc[mf][nf] = __builtin_amdgcn_mfma_f32_16x16x32_bf16(ah[mf], bh[nf], acc[mf][nf], 0, 0, 0);
                    acc[mf][nf] = __builtin_amdgcn_mfma_f32_16x16x32_bf16(ah[mf], bl[nf], acc[mf][nf], 0, 0, 0);
                }
        }
        __syncthreads();
    }
    float* Cf = (float*)Cptr;
    ushort* Cu = (ushort*)Cptr;
#pragma unroll
    for (int mf = 0; mf < 4; mf++)
#pragma unroll
        for (int nf = 0; nf < NF; nf++) {
            int colL = ny + wn * (BN / 2) + nf * 16 + (ln & 15);
#pragma unroll
            for (int j = 0; j < 4; j++) {
                int row = bm + wm * 64 + mf * 16 + (ln >> 4) * 4 + j;
                if (row < M) {
                    float v = acc[mf][nf][j];
                    if (ACT) {
                        v += bias[z * zC + colL];
                        v = v > 0.f ? v : (__expf(v) - 1.f);
                    }
                    size_t ci = (size_t)row * ldc + z * zC + colL;
                    if (OUTBF) Cu[ci] = f2bf_rne(v);
                    else       Cf[ci] = v;
                }
            }
        }
}

// ---- gru_h: elementwise GRU (h0=0) -> f32 h (output) + bf16 copy ----
__launch_bounds__(256)
__global__ void gru_h_kernel(const float* __restrict__ gi, const float* __restrict__ b_ih,
                             const float* __restrict__ b_hh, float* __restrict__ out_h,
                             ushort* __restrict__ h_bf) {
    int idx = blockIdx.x * 256 + threadIdx.x;   // 20000*128
    int n = idx >> 7, c = idx & 127;
    const float* g = gi + (size_t)n * 384;
    float ir = g[c] + b_ih[c];
    float iz = g[128 + c] + b_ih[128 + c];
    float ih = g[256 + c] + b_ih[256 + c];
    float r = 1.f / (1.f + __expf(-(ir + b_hh[c])));
    float z = 1.f / (1.f + __expf(-(iz + b_hh[128 + c])));
    float xx = ih + r * b_hh[256 + c];
    xx = fminf(fmaxf(xx, -15.f), 15.f);
    float e2 = __expf(2.f * xx);
    float nn = (e2 - 1.f) / (e2 + 1.f);
    float hv = (1.f - z) * nn;
    out_h[idx] = hv;
    h_bf[idx] = f2bf_rne(hv);
}

// ---- sir_epi: bias/cI/cR add + SIR recurrence ----
__launch_bounds__(256)
__global__ void sir_epi_kernel(const float* __restrict__ G, const float* __restrict__ wc,
                               const float* __restrict__ wb, const float* __restrict__ cI,
                               const float* __restrict__ cR, const float* __restrict__ Npop,
                               const float* __restrict__ I0, const float* __restrict__ R0,
                               float* __restrict__ predI, float* __restrict__ predR,
                               float* __restrict__ phyI, float* __restrict__ phyR) {
    int idx = blockIdx.x * 256 + threadIdx.x;   // 20000*32
    int n = idx >> 5, p = idx & 31;
    float civ = cI[n], crv = cR[n];
    float v = G[(size_t)n * 32 + p] + civ * wc[p * 2] + crv * wc[p * 2 + 1] + wb[p];
    if (p < 15) {
        predI[(size_t)n * 15 + p] = v;
    } else if (p < 30) {
        predR[(size_t)n * 15 + (p - 15)] = v;
    } else if (p == 30) {
        float v31 = G[(size_t)n * 32 + 31] + civ * wc[62] + crv * wc[63] + wb[31];
        float alpha = 1.f / (1.f + __expf(-v));
        float beta  = 1.f / (1.f + __expf(-v31));
        float Nv = Npop[n];
        float Iv = I0[n], Rv = R0[n];
        float SoN = (Nv - Iv - Rv) / Nv;
        for (int st = 0; st < 15; st++) {
            float dIv = alpha * Iv * SoN - beta * Iv;
            float dRv = beta * Iv;
            phyI[(size_t)n * 15 + st] = dIv;
            phyR[(size_t)n * 15 + st] = dRv;
            Iv += dIv; Rv += dRv;
        }
    }
}

extern "C" void kernel_launch(void* const* d_in, const int* in_sizes, int n_in,
                              void* d_out, int out_size, void* d_ws, size_t ws_size,
                              hipStream_t stream) {
    const float* dynamic = (const float*)d_in[0];
    const int*   ei      = (const int*)d_in[1];
    const float* cI      = (const float*)d_in[2];
    const float* cR      = (const float*)d_in[3];
    const float* Npop    = (const float*)d_in[4];
    const float* I0      = (const float*)d_in[5];
    const float* R0      = (const float*)d_in[6];
    const float* W1      = (const float*)d_in[9];
    const float* a_src1  = (const float*)d_in[10];
    const float* a_dst1  = (const float*)d_in[11];
    const float* b1      = (const float*)d_in[12];
    const float* W2      = (const float*)d_in[13];
    const float* a_src2  = (const float*)d_in[14];
    const float* a_dst2  = (const float*)d_in[15];
    const float* b2      = (const float*)d_in[16];
    const float* W_ih    = (const float*)d_in[17];
    const float* b_ih    = (const float*)d_in[19];
    const float* b_hh    = (const float*)d_in[20];
    const float* W_I     = (const float*)d_in[21];
    const float* b_I     = (const float*)d_in[22];
    const float* W_R     = (const float*)d_in[23];
    const float* b_R     = (const float*)d_in[24];
    const float* W_sir   = (const float*)d_in[25];
    const float* b_sir   = (const float*)d_in[26];
    float* out = (float*)d_out;
    float* out_predI = out;
    float* out_predR = out + 300000;
    float* out_phyI  = out + 600000;
    float* out_phyR  = out + 900000;
    float* out_h     = out + 1200000;   // [20000][128] f32

    // ---- workspace layout (~51 MB) ----
    int* wsi = (int*)d_ws;
    int* offs    = wsi;              // 20001 (pad 20096)
    int* csr_src = wsi + 20096;      // 660000 (pad 660096)
    int* cnt     = wsi + 680192;     // 32768
    int* sbase   = wsi + 712960;     // 32768
    float* fp = (float*)(wsi + 745728);
    float* w1f = fp; fp += 1152;     // 128*8
    float* wc  = fp; fp += 64;
    float* wb  = fp; fp += 64;
    float* al1 = fp; fp += 80128;    // 20000*4
    float* ar1 = fp; fp += 80128;
    float* al2 = fp; fp += 20096;
    float* ar2 = fp; fp += 20096;
    // pre-split bf16 weights (ushort)
    ushort* wub  = (ushort*)fp; fp += 118784;  // 237568 ushorts
    ushort* w1bh = wub;            // 32768
    ushort* w1bl = wub + 32768;
    ushort* w2bh = wub + 65536;    // 32768
    ushort* w2bl = wub + 98304;
    ushort* w3bh = wub + 131072;   // 49152 (W_ih^T [128][384])
    ushort* w3bl = wub + 180224;
    ushort* wthb = wub + 229376;   // 4096
    ushort* wtlb = wub + 233472;
    ushort* dyn_bf = (ushort*)fp; fp += 1280000;   // 20000*128 bf16 (5.12MB region)
    float* G = (float*)dyn_bf;                     // [20000][32] f32 (dyn dead by then)
    ushort* x1u = (ushort*)fp; fp += 2560000;      // [20000][256] bf16 (5.12MB region)
    ushort* x2u = x1u;                             // [20000][128] bf16 (x1 dead)
    ushort* h_bf = x1u + 2560000;                  // [20000][128] bf16 (2nd half)
    float* R  = fp; fp += 7680000;                 // ebuf / agg_bf / xl2_bf / gi
    int2* ebuf = (int2*)R;                         // [640000] int2
    ushort* agg_bf = (ushort*)R;                   // [20000][512] bf16
    ushort* xl2_bf = (ushort*)R;                   // [20000][128] bf16 (after agg dead)
    float* gi = R;                                 // [20000][384] f32 (after xl2 dead)

    // CSR build + weight prep
    csrA_kernel<<<NSL + 5, 256, 0, stream>>>(ei, cnt, W1, a_src1, a_dst1, w1f,
                                             W2, W_ih, W_I, b_I, W_R, b_R, W_sir, b_sir,
                                             w1bh, w1bl, w2bh, w2bl, w3bh, w3bl,
                                             wthb, wtlb, wc, wb);
    csrB_kernel<<<1, 1024, 0, stream>>>(cnt, sbase);
    csrC_kernel<<<NSL + 5000, 256, 0, stream>>>(ei, sbase, ebuf, dynamic, w1f,
                                                dyn_bf, al1, ar1);
    csrD_kernel<<<NB, 256, 0, stream>>>(ebuf, sbase, offs, csr_src);

    // GAT layer 1
    gat_gather_w<4, false><<<5000, 256, 0, stream>>>(dyn_bf, al1, ar1, offs, csr_src, nullptr, agg_bf);
    gemm_bf<1, true, 64><<<dim3(157, 1, 4), 256, 0, stream>>>(
        agg_bf, w1bh, w1bl, b1, x1u, NN, 128, 512, 256, 256, 128, 64, 64);

    // GAT layer 2
    gemm_bf<0, true, 128><<<dim3(157, 1, 1), 256, 0, stream>>>(
        x1u, w2bh, w2bl, nullptr, xl2_bf, NN, 256, 256, 128, 128, 0, 0, 0);
    alar_apply2<<<5000, 256, 0, stream>>>(xl2_bf, a_src2, a_dst2, al2, ar2);
    gat_gather_w<1, true><<<5000, 256, 0, stream>>>(xl2_bf, al2, ar2, offs, csr_src, b2, x2u);

    // gi = x2 @ W_ih^T  (B pre-transposed)
    gemm_bf<0, false, 128><<<dim3(157, 3, 1), 256, 0, stream>>>(
        x2u, w3bh, w3bl, nullptr, gi, NN, 128, 128, 384, 384, 0, 0, 0);

    // GRU elementwise -> h (f32 to output) + bf16 copy
    gru_h_kernel<<<10000, 256, 0, stream>>>(gi, b_ih, b_hh, out_h, h_bf);

    // heads: G = h @ Wt  (20000x128x32 MFMA)
    gemm_bf<0, false, 32><<<dim3(157, 1, 1), 256, 0, stream>>>(
        h_bf, wthb, wtlb, nullptr, G, NN, 128, 128, 32, 32, 0, 0, 0);

    // epilogue: cI/cR columns + bias, SIR recurrence
    sir_epi_kernel<<<2500, 256, 0, stream>>>(G, wc, wb, cI, cR, Npop, I0, R0,
                                             out_predI, out_predR, out_phyI, out_phyR);
}

// Round 10
// 222.204 us; speedup vs baseline: 1.1302x; 1.1302x over previous
//
#include <hip/hip_runtime.h>

#define NN 20000
#define NE 640000
#define NET (NE + NN)   // 660000 edges incl. self-loops
#define NB 128          // dst buckets
#define RR 157          // nodes per bucket (ceil 20000/128)
#define NSL 256         // edge slices
#define ESL4 625        // int4 per slice (2500 edges)

typedef __attribute__((ext_vector_type(8))) short bf16x8;
typedef __attribute__((ext_vector_type(4))) float f32x4;
typedef __attribute__((ext_vector_type(2))) float f32x2;

__device__ inline ushort f2bf_rne(float x) {
    unsigned u = __float_as_uint(x);
    return (ushort)((u + 0x7FFFu + ((u >> 16) & 1u)) >> 16);
}
__device__ inline float bf2f(ushort u) {
    return __uint_as_float(((unsigned)u) << 16);
}
__device__ inline void split2(float x, ushort& hi, ushort& lo) {
    unsigned u = __float_as_uint(x);
    unsigned r = (u + 0x7FFFu + ((u >> 16) & 1u)) & 0xFFFF0000u;  // RNE to bf16
    hi = (ushort)(r >> 16);
    lo = f2bf_rne(x - __uint_as_float(r));   // x - hi is exact
}
__device__ inline float rlane(float x, int k) {
    return __int_as_float(__builtin_amdgcn_readlane(__float_as_int(x), k));
}

// ---- csrA: per-slice bucket histogram + folds + weight pre-splits ----
__global__ void csrA_kernel(const int* __restrict__ ei, int* __restrict__ cnt,
                            const float* __restrict__ W1, const float* __restrict__ as1,
                            const float* __restrict__ ad1, float* __restrict__ w1f,
                            const float* __restrict__ W2, const float* __restrict__ as2,
                            const float* __restrict__ ad2, float* __restrict__ w2f,
                            const float* __restrict__ W_ih,
                            const float* __restrict__ W_I, const float* __restrict__ b_I,
                            const float* __restrict__ W_R, const float* __restrict__ b_R,
                            const float* __restrict__ W_sir, const float* __restrict__ b_sir,
                            ushort* __restrict__ w1bh, ushort* __restrict__ w1bl,
                            ushort* __restrict__ w2bh, ushort* __restrict__ w2bl,
                            ushort* __restrict__ w3bh, ushort* __restrict__ w3bl,
                            ushort* __restrict__ wthb, ushort* __restrict__ wtlb,
                            float* __restrict__ wc, float* __restrict__ wb) {
    int b = blockIdx.x, t = threadIdx.x;
    if (b < NSL) {
        __shared__ int h[NB];
        if (t < NB) h[t] = 0;
        __syncthreads();
        const int4* d4 = (const int4*)(ei + NE);
        for (int i = t; i < ESL4; i += 256) {
            int4 d = d4[b * ESL4 + i];
            atomicAdd(&h[(unsigned)d.x / RR], 1);
            atomicAdd(&h[(unsigned)d.y / RR], 1);
            atomicAdd(&h[(unsigned)d.z / RR], 1);
            atomicAdd(&h[(unsigned)d.w / RR], 1);
        }
        __syncthreads();
        if (t < NB) cnt[t * NSL + b] = h[t];   // bucket-major
    } else if (b == NSL) {
        if (t < 128) {
            int k = t;
#pragma unroll
            for (int hh = 0; hh < 4; hh++) {
                float s1 = 0.f, s2 = 0.f;
                for (int c = 0; c < 64; c++) {
                    float w = W1[k * 256 + hh * 64 + c];
                    s1 += w * as1[hh * 64 + c];
                    s2 += w * ad1[hh * 64 + c];
                }
                w1f[k * 8 + hh] = s1;
                w1f[k * 8 + 4 + hh] = s2;
            }
        }
    } else if (b == NSL + 1) {
        // w2f[k] = W2[k,:].a_src2 / .a_dst2  (k < 256)
        int k = t;
        float s1 = 0.f, s2 = 0.f;
        for (int c = 0; c < 128; c++) {
            float w = W2[k * 128 + c];
            s1 += w * as2[c];
            s2 += w * ad2[c];
        }
        w2f[k * 2] = s1;
        w2f[k * 2 + 1] = s2;
    } else if (b == NSL + 2) {
        // heads: Wt [32 n][128 k] bf16 split + wc (cols 128/129) + wb
        if (t < 128) {
            for (int p = 0; p < 32; p++) {
                const float* Wr = (p < 15) ? W_I + p * 130
                                : (p < 30) ? W_R + (p - 15) * 130
                                           : W_sir + (p - 30) * 130;
                ushort h, l;
                split2(Wr[t], h, l);
                wthb[p * 128 + t] = h;
                wtlb[p * 128 + t] = l;
            }
        } else if (t < 160) {
            int p = t - 128;
            const float* Wr = (p < 15) ? W_I + p * 130
                            : (p < 30) ? W_R + (p - 15) * 130
                                       : W_sir + (p - 30) * 130;
            wc[p * 2] = Wr[128];
            wc[p * 2 + 1] = Wr[129];
            wb[p] = (p < 15) ? b_I[p] : (p < 30) ? b_R[p - 15] : b_sir[p - 30];
        }
    } else if (b == NSL + 3) {
        for (int i = t; i < 128 * 256; i += 256) {
            ushort h, l; split2(W1[i], h, l);
            w1bh[i] = h; w1bl[i] = l;
        }
    } else if (b == NSL + 4) {
        for (int i = t; i < 256 * 128; i += 256) {
            ushort h, l; split2(W2[i], h, l);
            w2bh[i] = h; w2bl[i] = l;
        }
    } else {
        // W_ih^T: out[c][r] (c<128, r<384) = W_ih[r][c]
        for (int i = t; i < 128 * 384; i += 256) {
            int c = i / 384, r = i % 384;
            ushort h, l; split2(W_ih[r * 128 + c], h, l);
            w3bh[i] = h; w3bl[i] = l;
        }
    }
}

// ---- csrB: exclusive scan of 32768 counts, 32/thread (few barriers) ----
__global__ void csrB_kernel(const int* __restrict__ cnt, int* __restrict__ sbase) {
    __shared__ int ws1[16], ws2[16];
    int t = threadIdx.x, wv = t >> 6, ln = t & 63;
    int base = t * 32;
    int loc[32];
    int run = 0;
#pragma unroll
    for (int q = 0; q < 32; q++) { loc[q] = run; run += cnt[base + q]; }
    int s = run;
#pragma unroll
    for (int o = 1; o < 64; o <<= 1) { int u = __shfl_up(s, o, 64); if (ln >= o) s += u; }
    if (ln == 63) ws1[wv] = s;
    __syncthreads();
    if (t < 16) {
        int sv = ws1[t];
#pragma unroll
        for (int o = 1; o < 16; o <<= 1) { int u = __shfl_up(sv, o, 16); if (t >= o) sv += u; }
        ws2[t] = sv;
    }
    __syncthreads();
    int excl = (wv ? ws2[wv - 1] : 0) + s - run;
#pragma unroll
    for (int q = 0; q < 32; q++) sbase[base + q] = excl + loc[q];
}

// ---- csrC: slice scatter into ebuf + alar_cast ----
__global__ void csrC_kernel(const int* __restrict__ ei, const int* __restrict__ sbase,
                            int2* __restrict__ ebuf, const float* __restrict__ X,
                            const float* __restrict__ wf, ushort* __restrict__ Xbf,
                            float* __restrict__ al, float* __restrict__ ar) {
    int b = blockIdx.x, t = threadIdx.x;
    if (b < NSL) {
        __shared__ int cur[NB];
        if (t < NB) cur[t] = sbase[t * NSL + b];
        __syncthreads();
        const int4* s4 = (const int4*)ei;
        const int4* d4 = (const int4*)(ei + NE);
        for (int i = t; i < ESL4; i += 256) {
            int4 sv = s4[b * ESL4 + i];
            int4 dv = d4[b * ESL4 + i];
            int p;
            p = atomicAdd(&cur[(unsigned)dv.x / RR], 1); ebuf[p] = make_int2(sv.x, dv.x);
            p = atomicAdd(&cur[(unsigned)dv.y / RR], 1); ebuf[p] = make_int2(sv.y, dv.y);
            p = atomicAdd(&cur[(unsigned)dv.z / RR], 1); ebuf[p] = make_int2(sv.z, dv.z);
            p = atomicAdd(&cur[(unsigned)dv.w / RR], 1); ebuf[p] = make_int2(sv.w, dv.w);
        }
    } else {
        __shared__ float ws[8][128];
        for (int i = t; i < 1024; i += 256) ws[i & 7][i >> 3] = wf[i];
        __syncthreads();
        int wv = t >> 6, ln = t & 63;
        int n = (b - NSL) * 4 + wv;
        float2 xv = *(const float2*)(X + (size_t)n * 128 + ln * 2);
        ushort2 ub;
        ub.x = f2bf_rne(xv.x);
        ub.y = f2bf_rne(xv.y);
        *(ushort2*)(Xbf + (size_t)n * 128 + ln * 2) = ub;
        float p[8];
#pragma unroll
        for (int o = 0; o < 8; o++) p[o] = xv.x * ws[o][ln * 2] + xv.y * ws[o][ln * 2 + 1];
#pragma unroll
        for (int off = 32; off > 0; off >>= 1)
#pragma unroll
            for (int o = 0; o < 8; o++) p[o] += __shfl_xor(p[o], off, 64);
        if (ln == 0) {
#pragma unroll
            for (int h = 0; h < 4; h++) {
                al[n * 4 + h] = p[h];
                ar[n * 4 + h] = p[4 + h];
            }
        }
    }
}

// ---- csrD: per-bucket local CSR build ----
__global__ void csrD_kernel(const int2* __restrict__ ebuf, const int* __restrict__ sbase,
                            int* __restrict__ offs, int* __restrict__ csr_src) {
    __shared__ int hist[RR], lcur[RR];
    int b = blockIdx.x, t = threadIdx.x;
    int lo = b * RR;
    int Ra = min(RR, NN - lo);
    int e0 = sbase[b * NSL];
    int e1 = (b < NB - 1) ? sbase[(b + 1) * NSL] : NE;
    int m = e1 - e0;
    for (int i = t; i < Ra; i += 256) hist[i] = 0;
    __syncthreads();
    for (int j = t; j < m; j += 256) atomicAdd(&hist[ebuf[e0 + j].y - lo], 1);
    __syncthreads();
    if (t < 64) {
        int cbase = e0 + lo;
        int carry = 0;
#pragma unroll
        for (int c = 0; c < 3; c++) {
            int i = c * 64 + t;
            int v = (i < Ra) ? hist[i] + 1 : 0;   // +1 self-loop
            int s = v;
#pragma unroll
            for (int o = 1; o < 64; o <<= 1) { int u = __shfl_up(s, o, 64); if (t >= o) s += u; }
            if (i < Ra) {
                int off = cbase + carry + s - v;
                offs[lo + i] = off;
                lcur[i] = off;
            }
            carry += __shfl(s, 63, 64);
        }
    }
    if (b == 0 && t == 255) offs[NN] = NET;
    __syncthreads();
    for (int i = t; i < Ra; i += 256) csr_src[lcur[i] + hist[i]] = lo + i;  // self-loop last
    __syncthreads();
    for (int j = t; j < m; j += 256) {
        int2 p = ebuf[e0 + j];
        int pos = atomicAdd(&lcur[p.y - lo], 1);
        csr_src[pos] = p.x;
    }
}

// ---- GAT gather: wave/node, no-max softmax, packed-f32 FMA ----
template <int H, bool FUSE>
__launch_bounds__(256)
__global__ void gat_gather_w(const ushort* __restrict__ X, const float* __restrict__ al,
                             const float* __restrict__ ar, const int* __restrict__ offs,
                             const int* __restrict__ csr, const float* __restrict__ bias,
                             void* __restrict__ outp) {
    int t = threadIdx.x;
    int wv = t >> 6, ln = t & 63;
    int n = blockIdx.x * 4 + wv;
    int e0 = offs[n], e1 = offs[n + 1];

    float arv[H], srun[H];
    f32x2 acc2[H];
#pragma unroll
    for (int h = 0; h < H; h++) {
        arv[h] = ar[n * H + h];
        srun[h] = 0.f;
        acc2[h][0] = 0.f; acc2[h][1] = 0.f;
    }
    const ushort* Xc = X + ln * 2;

    for (int base = e0; base < e1; base += 64) {
        int cnt = e1 - base; if (cnt > 64) cnt = 64;
        bool vld = ln < cnt;
        int src = vld ? csr[base + ln] : 0;
        float wgt[H];
        {
            float av[H];
            if (H == 4) {
                float4 a4 = *(const float4*)(al + (size_t)src * 4);
                av[0] = a4.x; av[H > 1 ? 1 : 0] = a4.y;
                av[H > 2 ? 2 : 0] = a4.z; av[H > 3 ? 3 : 0] = a4.w;
            } else {
                av[0] = al[src];
            }
#pragma unroll
            for (int h = 0; h < H; h++) {
                float lg = av[h] + arv[h];
                lg = lg > 0.f ? lg : 0.2f * lg;
                wgt[h] = vld ? __expf(lg) : 0.f;
            }
        }
        float ls[H];
#pragma unroll
        for (int h = 0; h < H; h++) ls[h] = wgt[h];
#pragma unroll
        for (int off = 32; off > 0; off >>= 1)
#pragma unroll
            for (int h = 0; h < H; h++) ls[h] += __shfl_xor(ls[h], off, 64);
#pragma unroll
        for (int h = 0; h < H; h++) srun[h] += ls[h];

        int k = 0;
        for (; k + 8 <= cnt; k += 8) {
            int s[8];
            unsigned u[8];
#pragma unroll
            for (int q = 0; q < 8; q++) s[q] = __builtin_amdgcn_readlane(src, k + q);
#pragma unroll
            for (int q = 0; q < 8; q++) u[q] = *(const unsigned*)(Xc + (size_t)s[q] * 128);
#pragma unroll
            for (int q = 0; q < 8; q++) {
                f32x2 xv;
                xv[0] = __uint_as_float(u[q] << 16);
                xv[1] = __uint_as_float(u[q] & 0xffff0000u);
#pragma unroll
                for (int h = 0; h < H; h++) {
                    float w = rlane(wgt[h], k + q);
                    f32x2 ww; ww[0] = w; ww[1] = w;
                    acc2[h] = __builtin_elementwise_fma(ww, xv, acc2[h]);
                }
            }
        }
        for (; k < cnt; k++) {
            int s0 = __builtin_amdgcn_readlane(src, k);
            unsigned u0 = *(const unsigned*)(Xc + (size_t)s0 * 128);
            f32x2 xv;
            xv[0] = __uint_as_float(u0 << 16);
            xv[1] = __uint_as_float(u0 & 0xffff0000u);
#pragma unroll
            for (int h = 0; h < H; h++) {
                float w = rlane(wgt[h], k);
                f32x2 ww; ww[0] = w; ww[1] = w;
                acc2[h] = __builtin_elementwise_fma(ww, xv, acc2[h]);
            }
        }
    }
    if (FUSE) {
        ushort* out = (ushort*)outp;
        float inv = 1.f / srun[0];
        float v0 = acc2[0][0] * inv + bias[ln * 2];
        float v1 = acc2[0][1] * inv + bias[ln * 2 + 1];
        v0 = v0 > 0.f ? v0 : __expf(v0) - 1.f;
        v1 = v1 > 0.f ? v1 : __expf(v1) - 1.f;
        ushort2 o;
        o.x = f2bf_rne(v0);
        o.y = f2bf_rne(v1);
        *(ushort2*)(out + (size_t)n * 128 + ln * 2) = o;
    } else {
        ushort* out = (ushort*)outp;
#pragma unroll
        for (int h = 0; h < H; h++) {
            float inv = 1.f / srun[h];
            ushort2 o;
            o.x = f2bf_rne(acc2[h][0] * inv);
            o.y = f2bf_rne(acc2[h][1] * inv);
            *(ushort2*)(out + (size_t)n * (H * 128) + h * 128 + ln * 2) = o;
        }
    }
}

// ---- MFMA bf16 GEMM: A bf16, B pre-split hi/lo bf16; optional fused alar ----
template <int ACT, bool OUTBF, int BN, bool ALAR>
__launch_bounds__(256)
__global__ void gemm_bf(const ushort* __restrict__ A, const ushort* __restrict__ Bh_pre,
                        const ushort* __restrict__ Bl_pre, const float* __restrict__ bias,
                        void* __restrict__ Cptr, int M, int K, int lda, int ldb, int ldc,
                        int zA, int zB, int zC, const float* __restrict__ w2f,
                        float* __restrict__ al2, float* __restrict__ ar2) {
    constexpr int NF = BN / 32;
    __shared__ ushort Ah[128 * 64];
    __shared__ ushort Bh[64 * BN];
    __shared__ ushort Bl[64 * BN];
    __shared__ float s_w2f[ALAR ? 256 : 1][2];
    int tid = threadIdx.x;
    int z = blockIdx.z;
    int bm = blockIdx.x * 128;
    int ny = blockIdx.y * BN;
    int wid = tid >> 6, ln = tid & 63;
    int wm = wid >> 1, wn = wid & 1;
    f32x4 acc[4][NF];
#pragma unroll
    for (int a = 0; a < 4; a++)
#pragma unroll
        for (int b = 0; b < NF; b++)
#pragma unroll
            for (int j = 0; j < 4; j++) acc[a][b][j] = 0.f;
    float p0a[8], p1a[8];
    if (ALAR) {
#pragma unroll
        for (int i = 0; i < 8; i++) { p0a[i] = 0.f; p1a[i] = 0.f; }
        s_w2f[tid][0] = w2f[tid * 2];
        s_w2f[tid][1] = w2f[tid * 2 + 1];
        __syncthreads();
    }
    size_t abase = (size_t)z * zA;
    int bcb = z * zB + ny;

    for (int k0 = 0; k0 < K; k0 += 64) {
#pragma unroll
        for (int i = 0; i < 8; i++) {
            int idx = tid + i * 256;
            int r = idx >> 4, c4 = (idx & 15) * 4;
            int gr = bm + r;
            ushort4 v = make_ushort4(0, 0, 0, 0);
            if (gr < M) v = *(const ushort4*)(A + abase + (size_t)gr * lda + k0 + c4);
            int ab = (r * 128 + c4 * 2) ^ ((r & 7) << 4);
            *(ushort4*)((char*)Ah + ab) = v;
            if (ALAR) {
                int kk = k0 + c4;
                float x0 = bf2f(v.x), x1 = bf2f(v.y), x2 = bf2f(v.z), x3 = bf2f(v.w);
                p0a[i] = fmaf(x0, s_w2f[kk][0], p0a[i]);
                p0a[i] = fmaf(x1, s_w2f[kk + 1][0], p0a[i]);
                p0a[i] = fmaf(x2, s_w2f[kk + 2][0], p0a[i]);
                p0a[i] = fmaf(x3, s_w2f[kk + 3][0], p0a[i]);
                p1a[i] = fmaf(x0, s_w2f[kk][1], p1a[i]);
                p1a[i] = fmaf(x1, s_w2f[kk + 1][1], p1a[i]);
                p1a[i] = fmaf(x2, s_w2f[kk + 2][1], p1a[i]);
                p1a[i] = fmaf(x3, s_w2f[kk + 3][1], p1a[i]);
            }
        }
#pragma unroll
        for (int i = 0; i < BN / 16; i++) {
            int idx = tid + i * 256;
            int kk = idx / (BN / 4);
            int c4 = (idx % (BN / 4)) * 4;
            size_t gb = (size_t)(k0 + kk) * ldb + bcb + c4;
            ushort4 vh = *(const ushort4*)(Bh_pre + gb);
            ushort4 vl = *(const ushort4*)(Bl_pre + gb);
            ushort hh[4] = {vh.x, vh.y, vh.z, vh.w};
            ushort ll[4] = {vl.x, vl.y, vl.z, vl.w};
#pragma unroll
            for (int q = 0; q < 4; q++) {
                int nl = c4 + q;
                int bb = (nl * 128 + kk * 2) ^ ((nl & 7) << 4);
                *(ushort*)((char*)Bh + bb) = hh[q];
                *(ushort*)((char*)Bl + bb) = ll[q];
            }
        }
        __syncthreads();
#pragma unroll
        for (int ks = 0; ks < 2; ks++) {
            int kb = ks * 64 + (ln >> 4) * 16;
            bf16x8 ah[4], bh[NF], bl[NF];
#pragma unroll
            for (int mf = 0; mf < 4; mf++) {
                int r = wm * 64 + mf * 16 + (ln & 15);
                int ab = (r * 128 + kb) ^ ((r & 7) << 4);
                ah[mf] = *(bf16x8*)((char*)Ah + ab);
            }
#pragma unroll
            for (int nf = 0; nf < NF; nf++) {
                int nl = wn * (BN / 2) + nf * 16 + (ln & 15);
                int bb = (nl * 128 + kb) ^ ((nl & 7) << 4);
                bh[nf] = *(bf16x8*)((char*)Bh + bb);
                bl[nf] = *(bf16x8*)((char*)Bl + bb);
            }
#pragma unroll
            for (int mf = 0; mf < 4; mf++)
#pragma unroll
                for (int nf = 0; nf < NF; nf++) {
                    acc[mf][nf] = __builtin_amdgcn_mfma_f32_16x16x32_bf16(ah[mf], bh[nf], acc[mf][nf], 0, 0, 0);
                    acc[mf][nf] = __builtin_amdgcn_mfma_f32_16x16x32_bf16(ah[mf], bl[nf], acc[mf][nf], 0, 0, 0);
                }
        }
        __syncthreads();
    }
    if (ALAR) {
#pragma unroll
        for (int i = 0; i < 8; i++) {
            float p0 = p0a[i], p1 = p1a[i];
#pragma unroll
            for (int off = 8; off > 0; off >>= 1) {
                p0 += __shfl_xor(p0, off, 16);
                p1 += __shfl_xor(p1, off, 16);
            }
            if ((tid & 15) == 0) {
                int gr = bm + (tid >> 4) + i * 16;
                if (gr < M) { al2[gr] = p0; ar2[gr] = p1; }
            }
        }
    }
    float* Cf = (float*)Cptr;
    ushort* Cu = (ushort*)Cptr;
#pragma unroll
    for (int mf = 0; mf < 4; mf++)
#pragma unroll
        for (int nf = 0; nf < NF; nf++) {
            int colL = ny + wn * (BN / 2) + nf * 16 + (ln & 15);
#pragma unroll
            for (int j = 0; j < 4; j++) {
                int row = bm + wm * 64 + mf * 16 + (ln >> 4) * 4 + j;
                if (row < M) {
                    float v = acc[mf][nf][j];
                    if (ACT) {
                        v += bias[z * zC + colL];
                        v = v > 0.f ? v : (__expf(v) - 1.f);
                    }
                    size_t ci = (size_t)row * ldc + z * zC + colL;
                    if (OUTBF) Cu[ci] = f2bf_rne(v);
                    else       Cf[ci] = v;
                }
            }
        }
}

// ---- tail: GRU elementwise + heads MFMA + bias/cI/cR + SIR, 64 nodes/block ----
__launch_bounds__(256)
__global__ void tail_kernel(const float* __restrict__ gi, const float* __restrict__ b_ih,
                            const float* __restrict__ b_hh, const ushort* __restrict__ wthb,
                            const ushort* __restrict__ wtlb, const float* __restrict__ wc,
                            const float* __restrict__ wb, const float* __restrict__ cI,
                            const float* __restrict__ cR, const float* __restrict__ Npop,
                            const float* __restrict__ I0, const float* __restrict__ R0,
                            float* __restrict__ out_h, float* __restrict__ predI,
                            float* __restrict__ predR, float* __restrict__ phyI,
                            float* __restrict__ phyR) {
    __shared__ ushort As[64 * 128];               // swizzled h tile, 16 KB
    __shared__ ushort Bh[32 * 128], Bl[32 * 128]; // Wt hi/lo, 8+8 KB
    __shared__ float s_ab[2][64];
    __shared__ float s_ci[64], s_cr[64];
    int t = threadIdx.x;
    int bm = blockIdx.x * 64;
    // stage B (Wt [32 n][128 k])
    for (int i = t; i < 1024; i += 256) {
        int nl = i >> 5, k4 = (i & 31) * 4;
        ushort4 vh = *(const ushort4*)(wthb + nl * 128 + k4);
        ushort4 vl = *(const ushort4*)(wtlb + nl * 128 + k4);
        int bb = (nl * 256 + k4 * 2) ^ ((nl & 7) << 4);
        *(ushort4*)((char*)Bh + bb) = vh;
        *(ushort4*)((char*)Bl + bb) = vl;
    }
    if (t < 64) {
        int n = bm + t;
        s_ci[t] = (n < NN) ? cI[n] : 0.f;
        s_cr[t] = (n < NN) ? cR[n] : 0.f;
    }
    // GRU elementwise: 2048 (node, c4) pieces
    for (int i = t; i < 2048; i += 256) {
        int r = i >> 5, c4 = (i & 31) * 4;
        int n = bm + r;
        float4 ga, gb, gc;
        if (n < NN) {
            const float* g = gi + (size_t)n * 384;
            ga = *(const float4*)(g + c4);
            gb = *(const float4*)(g + 128 + c4);
            gc = *(const float4*)(g + 256 + c4);
        } else {
            ga = make_float4(0.f, 0.f, 0.f, 0.f); gb = ga; gc = ga;
        }
        float gaa[4] = {ga.x, ga.y, ga.z, ga.w};
        float gba[4] = {gb.x, gb.y, gb.z, gb.w};
        float gca[4] = {gc.x, gc.y, gc.z, gc.w};
        float hv[4];
#pragma unroll
        for (int q = 0; q < 4; q++) {
            int c = c4 + q;
            float rr = 1.f / (1.f + __expf(-(gaa[q] + b_ih[c] + b_hh[c])));
            float zz = 1.f / (1.f + __expf(-(gba[q] + b_ih[128 + c] + b_hh[128 + c])));
            float xx = gca[q] + b_ih[256 + c] + rr * b_hh[256 + c];
            xx = fminf(fmaxf(xx, -15.f), 15.f);
            float e2 = __expf(2.f * xx);
            hv[q] = (1.f - zz) * (e2 - 1.f) / (e2 + 1.f);
        }
        if (n < NN)
            *(float4*)(out_h + (size_t)n * 128 + c4) = make_float4(hv[0], hv[1], hv[2], hv[3]);
        ushort4 hb = make_ushort4(f2bf_rne(hv[0]), f2bf_rne(hv[1]), f2bf_rne(hv[2]), f2bf_rne(hv[3]));
        int ab = (r * 256 + c4 * 2) ^ ((r & 7) << 4);
        *(ushort4*)((char*)As + ab) = hb;
    }
    __syncthreads();
    // MFMA: wave wid -> rows wid*16..+15, all 32 cols
    int wid = t >> 6, ln = t & 63;
    f32x4 acc[2];
#pragma unroll
    for (int nf = 0; nf < 2; nf++)
#pragma unroll
        for (int j = 0; j < 4; j++) acc[nf][j] = 0.f;
#pragma unroll
    for (int ks = 0; ks < 4; ks++) {
        int kb = ks * 64 + (ln >> 4) * 16;
        int r = wid * 16 + (ln & 15);
        int ab = (r * 256 + kb) ^ ((r & 7) << 4);
        bf16x8 ah = *(bf16x8*)((char*)As + ab);
#pragma unroll
        for (int nf = 0; nf < 2; nf++) {
            int nl = nf * 16 + (ln & 15);
            int bb = (nl * 256 + kb) ^ ((nl & 7) << 4);
            bf16x8 bhv = *(bf16x8*)((char*)Bh + bb);
            bf16x8 blv = *(bf16x8*)((char*)Bl + bb);
            acc[nf] = __builtin_amdgcn_mfma_f32_16x16x32_bf16(ah, bhv, acc[nf], 0, 0, 0);
            acc[nf] = __builtin_amdgcn_mfma_f32_16x16x32_bf16(ah, blv, acc[nf], 0, 0, 0);
        }
    }
    // epilogue
#pragma unroll
    for (int nf = 0; nf < 2; nf++) {
        int col = nf * 16 + (ln & 15);
#pragma unroll
        for (int j = 0; j < 4; j++) {
            int rl = wid * 16 + (ln >> 4) * 4 + j;
            int n = bm + rl;
            float v = acc[nf][j] + s_ci[rl] * wc[col * 2] + s_cr[rl] * wc[col * 2 + 1] + wb[col];
            if (n < NN) {
                if (col < 15)      predI[(size_t)n * 15 + col] = v;
                else if (col < 30) predR[(size_t)n * 15 + col - 15] = v;
            }
            if (col == 30) s_ab[0][rl] = v;
            if (col == 31) s_ab[1][rl] = v;
        }
    }
    __syncthreads();
    if (t < 64) {
        int n = bm + t;
        if (n < NN) {
            float alpha = 1.f / (1.f + __expf(-s_ab[0][t]));
            float beta  = 1.f / (1.f + __expf(-s_ab[1][t]));
            float Nv = Npop[n];
            float Iv = I0[n], Rv = R0[n];
            float SoN = (Nv - Iv - Rv) / Nv;
            for (int st = 0; st < 15; st++) {
                float dI = alpha * Iv * SoN - beta * Iv;
                float dR = beta * Iv;
                phyI[(size_t)n * 15 + st] = dI;
                phyR[(size_t)n * 15 + st] = dR;
                Iv += dI; Rv += dR;
            }
        }
    }
}

extern "C" void kernel_launch(void* const* d_in, const int* in_sizes, int n_in,
                              void* d_out, int out_size, void* d_ws, size_t ws_size,
                              hipStream_t stream) {
    const float* dynamic = (const float*)d_in[0];
    const int*   ei      = (const int*)d_in[1];
    const float* cI      = (const float*)d_in[2];
    const float* cR      = (const float*)d_in[3];
    const float* Npop    = (const float*)d_in[4];
    const float* I0      = (const float*)d_in[5];
    const float* R0      = (const float*)d_in[6];
    const float* W1      = (const float*)d_in[9];
    const float* a_src1  = (const float*)d_in[10];
    const float* a_dst1  = (const float*)d_in[11];
    const float* b1      = (const float*)d_in[12];
    const float* W2      = (const float*)d_in[13];
    const float* a_src2  = (const float*)d_in[14];
    const float* a_dst2  = (const float*)d_in[15];
    const float* b2      = (const float*)d_in[16];
    const float* W_ih    = (const float*)d_in[17];
    const float* b_ih    = (const float*)d_in[19];
    const float* b_hh    = (const float*)d_in[20];
    const float* W_I     = (const float*)d_in[21];
    const float* b_I     = (const float*)d_in[22];
    const float* W_R     = (const float*)d_in[23];
    const float* b_R     = (const float*)d_in[24];
    const float* W_sir   = (const float*)d_in[25];
    const float* b_sir   = (const float*)d_in[26];
    float* out = (float*)d_out;
    float* out_predI = out;
    float* out_predR = out + 300000;
    float* out_phyI  = out + 600000;
    float* out_phyR  = out + 900000;
    float* out_h     = out + 1200000;   // [20000][128] f32

    // ---- workspace layout ----
    int* wsi = (int*)d_ws;
    int* offs    = wsi;              // 20001 (pad 20096)
    int* csr_src = wsi + 20096;      // 660000 (pad 660096)
    int* cnt     = wsi + 680192;     // 32768
    int* sbase   = wsi + 712960;     // 32768
    float* fp = (float*)(wsi + 745728);
    float* w1f = fp; fp += 1152;     // 128*8
    float* w2f = fp; fp += 512;      // 256*2
    float* wc  = fp; fp += 64;
    float* wb  = fp; fp += 64;
    float* al1 = fp; fp += 80128;    // 20000*4
    float* ar1 = fp; fp += 80128;
    float* al2 = fp; fp += 20096;
    float* ar2 = fp; fp += 20096;
    // pre-split bf16 weights (ushort)
    ushort* wub  = (ushort*)fp; fp += 118784;  // 237568 ushorts
    ushort* w1bh = wub;            // 32768
    ushort* w1bl = wub + 32768;
    ushort* w2bh = wub + 65536;    // 32768
    ushort* w2bl = wub + 98304;
    ushort* w3bh = wub + 131072;   // 49152 (W_ih^T [128][384])
    ushort* w3bl = wub + 180224;
    ushort* wthb = wub + 229376;   // 4096 (Wt [32][128])
    ushort* wtlb = wub + 233472;
    ushort* dyn_bf = (ushort*)fp; fp += 1280000;   // 20000*128 bf16
    ushort* x1u = (ushort*)fp; fp += 2560000;      // [20000][256] bf16
    ushort* x2u = x1u;                             // [20000][128] bf16 (x1 dead)
    float* R  = fp; fp += 7680000;                 // ebuf / agg_bf / xl2_bf / gi
    int2* ebuf = (int2*)R;                         // [640000] int2
    ushort* agg_bf = (ushort*)R;                   // [20000][512] bf16
    ushort* xl2_bf = (ushort*)R;                   // [20000][128] bf16 (after agg dead)
    float* gi = R;                                 // [20000][384] f32 (after xl2 dead)

    // CSR build + weight prep
    csrA_kernel<<<NSL + 6, 256, 0, stream>>>(ei, cnt, W1, a_src1, a_dst1, w1f,
                                             W2, a_src2, a_dst2, w2f, W_ih,
                                             W_I, b_I, W_R, b_R, W_sir, b_sir,
                                             w1bh, w1bl, w2bh, w2bl, w3bh, w3bl,
                                             wthb, wtlb, wc, wb);
    csrB_kernel<<<1, 1024, 0, stream>>>(cnt, sbase);
    csrC_kernel<<<NSL + 5000, 256, 0, stream>>>(ei, sbase, ebuf, dynamic, w1f,
                                                dyn_bf, al1, ar1);
    csrD_kernel<<<NB, 256, 0, stream>>>(ebuf, sbase, offs, csr_src);

    // GAT layer 1
    gat_gather_w<4, false><<<5000, 256, 0, stream>>>(dyn_bf, al1, ar1, offs, csr_src, nullptr, agg_bf);
    gemm_bf<1, true, 64, false><<<dim3(157, 1, 4), 256, 0, stream>>>(
        agg_bf, w1bh, w1bl, b1, x1u, NN, 128, 512, 256, 256, 128, 64, 64,
        nullptr, nullptr, nullptr);

    // GAT layer 2 (al2/ar2 fused into GEMM via w2f fold)
    gemm_bf<0, true, 128, true><<<dim3(157, 1, 1), 256, 0, stream>>>(
        x1u, w2bh, w2bl, nullptr, xl2_bf, NN, 256, 256, 128, 128, 0, 0, 0,
        w2f, al2, ar2);
    gat_gather_w<1, true><<<5000, 256, 0, stream>>>(xl2_bf, al2, ar2, offs, csr_src, b2, x2u);

    // gi = x2 @ W_ih^T  (B pre-transposed)
    gemm_bf<0, false, 128, false><<<dim3(157, 3, 1), 256, 0, stream>>>(
        x2u, w3bh, w3bl, nullptr, gi, NN, 128, 128, 384, 384, 0, 0, 0,
        nullptr, nullptr, nullptr);

    // GRU + heads MFMA + SIR, fused
    tail_kernel<<<313, 256, 0, stream>>>(gi, b_ih, b_hh, wthb, wtlb, wc, wb,
                                         cI, cR, Npop, I0, R0, out_h,
                                         out_predI, out_predR, out_phyI, out_phyR);
}